// Round 12
// baseline (1653.848 us; speedup 1.0000x reference)
//
#include <hip/hip_runtime.h>
#include <hip/hip_bf16.h>
#include <hip/hip_fp16.h>

#define Dd 64
#define Hh 128
#define Ww 128
#define Cc 32

// block tile: 32d x 16h x 16w outputs; wave = 8d x 16h x 16w
#define BD 32
#define BH 16
#define BW 16
#define ZR (BD + 6)        // 38 staged z-planes
#define HR (BH + 6)        // 22 staged h-rows
#define NR (ZR * HR)       // 836 rows
#define RCOLS 24           // bf16 cols per row; col = w - w0 + 4 (left halo 4)
#define BLKROW 3
#define NBLK (NR * BLKROW) // 2508 16B blocks to stage

// A-fragment table: 49 7^3-planes x 14 windows + 9 3^3-planes x 10 windows
// + 1 shared all-zero entry. 777 entries x 16B per channel.
#define N7WIN 14
#define N3WIN 10
#define W3BASE (49 * N7WIN)          // 686
#define ZENT   (W3BASE + 9 * N3WIN) // 776
#define NENT   (ZENT + 1)           // 777
#define WTAB_BYTES ((size_t)Cc * NENT * 16)   // 397,824 B in d_ws

typedef __attribute__((ext_vector_type(8))) short short8;   // 8 bf16 (4 VGPR)
typedef __attribute__((ext_vector_type(4))) float floatx4;  // MFMA acc

static __device__ __forceinline__ unsigned short f2bf(float f) {
    unsigned u = __builtin_bit_cast(unsigned, f);
    u += 0x7fffu + ((u >> 16) & 1u);   // RNE
    return (unsigned short)(u >> 16);
}

static __device__ __forceinline__ unsigned pk2(float a, float b) {
    union { __hip_bfloat162 h; unsigned u; } cv;
    cv.h = __float22bfloat162_rn(make_float2(a, b));   // v_cvt_pk_bf16_f32
    return cv.u;
}

static __device__ __forceinline__ short8 as_s8(uint4 v) {
    union { uint4 u; short8 s; } cv; cv.u = v; return cv.s;
}

// GW=true: A-table in global d_ws (self-built, idempotent) -> LDS = tile only
//          (40128 -> 40960 granule -> 4 blocks/CU).
// GW=false: fallback, table in LDS (3 blocks/CU) when ws_size is too small.
template <bool GW>
__global__ __launch_bounds__(256, GW ? 4 : 3) void replk_mfma(
    const float* __restrict__ x,
    const float* __restrict__ w7, const float* __restrict__ w3, const float* __restrict__ w1,
    const float* __restrict__ g7, const float* __restrict__ b7, const float* __restrict__ m7, const float* __restrict__ v7,
    const float* __restrict__ g3, const float* __restrict__ b3, const float* __restrict__ m3, const float* __restrict__ v3,
    const float* __restrict__ g1, const float* __restrict__ b1, const float* __restrict__ m1, const float* __restrict__ v1,
    uint4* __restrict__ gtab,
    float* __restrict__ out)
{
    __shared__ __align__(16) unsigned short tile[NR * RCOLS];        // 40128 B
    __shared__ __align__(16) unsigned short wtab_l[GW ? 8 : NENT * 8];

    const int tid = threadIdx.x;

    // XCD-aware swizzle: 8192 blocks, 8 XCDs, 1024 contiguous per XCD.
    const unsigned lid = blockIdx.x;
    const unsigned nl = (lid & 7u) * 1024u + (lid >> 3);
    const int bx = nl & 127;
    const int slab = nl >> 7;
    const int c = slab & 31;
    const int nb = slab >> 5;
    const int w0 = (bx & 7) * BW;
    const int h0 = ((bx >> 3) & 7) * BH;
    const int d0 = (bx >> 6) * BD;

    const float* xc = x + (size_t)(nb * Cc + c) * (Dd * Hh * Ww);
    uint4* gc = gtab + (size_t)c * NENT;

    // ---- build A-fragment table (global when GW, idempotent across blocks) ----
    for (int e = tid; e < NENT; e += 256) {
        unsigned short h8[8];
#pragma unroll
        for (int j = 0; j < 8; j++) {
            float v = 0.f;
            if (e < W3BASE) {
                int pl = e / N7WIN, a = e - pl * N7WIN;
                int t = a + j - 7;
                if ((unsigned)t < 7u)
                    v = w7[c * 343 + (pl / 7) * 49 + (pl % 7) * 7 + t];
            } else if (e < ZENT) {
                int e2 = e - W3BASE;
                int p3 = e2 / N3WIN, a = e2 - p3 * N3WIN;
                int t = a + j - 7;
                if ((unsigned)t < 3u)
                    v = w3[c * 27 + (p3 / 3) * 9 + (p3 % 3) * 3 + t];
            }
            h8[j] = f2bf(v);
        }
        uint4 pk;
        pk.x = (unsigned)h8[0] | ((unsigned)h8[1] << 16);
        pk.y = (unsigned)h8[2] | ((unsigned)h8[3] << 16);
        pk.z = (unsigned)h8[4] | ((unsigned)h8[5] << 16);
        pk.w = (unsigned)h8[6] | ((unsigned)h8[7] << 16);
        if constexpr (GW) gc[e] = pk;
        else *(uint4*)&wtab_l[e * 8] = pk;
    }

    // ---- stage input tile fp32 -> bf16 (cvt_pk), 24 cols/row, left halo 4 ----
#pragma unroll
    for (int it = 0; it < 10; it++) {
        int s = tid + it * 256;
        if (s < NBLK) {
            int R = s / BLKROW, bl = s - R * BLKROW;
            int zi = R / HR, hr = R - zi * HR;
            int gz = d0 - 3 + zi, gh = h0 - 3 + hr, gw0 = w0 - 4 + bl * 8;
            float v[8];
#pragma unroll
            for (int j = 0; j < 8; j++) v[j] = 0.f;
            if ((unsigned)gz < (unsigned)Dd && (unsigned)gh < (unsigned)Hh) {
                const float* src = xc + ((size_t)gz * Hh + gh) * Ww + gw0;
                if (gw0 >= 0 && gw0 + 8 <= Ww) {
                    float4 a = *(const float4*)src;
                    float4 b = *(const float4*)(src + 4);
                    v[0] = a.x; v[1] = a.y; v[2] = a.z; v[3] = a.w;
                    v[4] = b.x; v[5] = b.y; v[6] = b.z; v[7] = b.w;
                } else {
#pragma unroll
                    for (int j = 0; j < 8; j++) {
                        int gw = gw0 + j;
                        if ((unsigned)gw < (unsigned)Ww) v[j] = src[j];
                    }
                }
            }
            uint4 pk;
            pk.x = pk2(v[0], v[1]);
            pk.y = pk2(v[2], v[3]);
            pk.z = pk2(v[4], v[5]);
            pk.w = pk2(v[6], v[7]);
            *(uint4*)&tile[R * RCOLS + bl * 8] = pk;
        }
    }

    // BN constants (wave-uniform)
    const float eps = 1e-5f;
    const float iv7 = g7[c] / sqrtf(v7[c] + eps);
    const float bb7 = b7[c] - m7[c] * iv7;
    const float iv3 = g3[c] / sqrtf(v3[c] + eps);
    const float bb3 = b3[c] - m3[c] * iv3;
    const float iv1 = g1[c] / sqrtf(v1[c] + eps);
    const float bb1 = b1[c] - m1[c] * iv1;
    const float s1 = w1[c] * iv1;

    if constexpr (GW) __threadfence();   // own-block table writes -> visible
    __syncthreads();

    const int lane = tid & 63;
    const int wave = tid >> 6;
    const int q = lane & 15;          // m (A) / n (B,C,D)
    const int p = lane >> 4;
    const int khp = p >> 1;           // kh within pair
    const int kb  = p & 1;            // wc 16B-block
    const int ddl = q >> 3;           // d within M-pair (A side)
    const int mwq = q & 7;            // w within M (A side)
    const int zbase = wave * 8;       // wave owns d-outputs [zbase, zbase+8)

    const int a7 = 8 * kb - mwq + 6;  // 7^3 window (valid [0,14))
    const int a3 = a7 - 2;            // 3^3 window (valid [0,10))

    auto LDA = [&](int idx) -> short8 {
        if constexpr (GW) return as_s8(gc[idx]);
        else return ((const short8*)wtab_l)[idx];
    };

    floatx4 acc[4][2];
#pragma unroll
    for (int i = 0; i < 4; i++) { acc[i][0] = (floatx4)0.f; acc[i][1] = (floatx4)0.f; }

    // ================= phase 1: 3^3 branch (acc -> y3 packed f16) ===========
    const bool ok3base = (unsigned)a3 < (unsigned)N3WIN;
#pragma unroll 1
    for (int k3g = 0; k3g < 2; k3g++) {
        const int kh3 = 2 * k3g + khp;                     // 0..3 (3 = zero)
        const bool ok3 = ok3base && (kh3 <= 2);
        const int cb3 = ok3 ? (W3BASE + kh3 * 10 + a3 - ddl * 30) : (int)ZENT;
        const int st3 = ok3 ? 30 : 0;
        short8 A3g[4];
#pragma unroll
        for (int rz = 0; rz < 4; rz++) {
            int idx = cb3 + rz * st3;
            if (rz == 0) idx = (ddl == 0 && ok3) ? idx : (int)ZENT;
            if (rz == 3) idx = (ddl == 1 && ok3) ? idx : (int)ZENT;
            A3g[rz] = LDA(idx);
        }
        const int rowadd3 = (kh3 <= 2 ? kh3 : 2) + 2;

#pragma unroll
        for (int zi = 2; zi < 12; zi++) {
            const int R = (zbase + zi) * HR + q + rowadd3;
            const unsigned short* bp = &tile[R * RCOLS + 8 * kb];
            short8 B0 = *(const short8*)bp;
            short8 B1 = *(const short8*)(bp + 8);
            __builtin_amdgcn_s_setprio(1);
#pragma unroll
            for (int ddg = 0; ddg < 4; ddg++) {
                const int rz3 = zi - 2 - 2 * ddg;
                if (rz3 >= 0 && rz3 < 4) {
                    acc[ddg][0] = __builtin_amdgcn_mfma_f32_16x16x32_bf16(
                        A3g[rz3], B0, acc[ddg][0], 0, 0, 0);
                    acc[ddg][1] = __builtin_amdgcn_mfma_f32_16x16x32_bf16(
                        A3g[rz3], B1, acc[ddg][1], 0, 0, 0);
                }
            }
            __builtin_amdgcn_s_setprio(0);
        }
    }

    // BN + ReLU the 3^3 branch, pack to f16, free acc for the 7^3 branch
    __half2 y3p[4][2][2];
#pragma unroll
    for (int ddg = 0; ddg < 4; ddg++)
#pragma unroll
        for (int wh = 0; wh < 2; wh++) {
            float t0 = fmaxf(fmaf(acc[ddg][wh][0], iv3, bb3), 0.f);
            float t1 = fmaxf(fmaf(acc[ddg][wh][1], iv3, bb3), 0.f);
            float t2 = fmaxf(fmaf(acc[ddg][wh][2], iv3, bb3), 0.f);
            float t3 = fmaxf(fmaf(acc[ddg][wh][3], iv3, bb3), 0.f);
            y3p[ddg][wh][0] = __float22half2_rn(make_float2(t0, t1));
            y3p[ddg][wh][1] = __float22half2_rn(make_float2(t2, t3));
            acc[ddg][wh] = (floatx4)0.f;
        }

    // ================= phase 2: 7^3 branch =================================
    const bool ok7base = (unsigned)a7 < (unsigned)N7WIN;
#pragma unroll 1
    for (int khg = 0; khg < 4; khg++) {
        const int kh = 2 * khg + khp;                      // 0..7 (7 = zero)
        const bool ok7 = ok7base && (kh <= 6);
        const int cb7 = ok7 ? (kh * 14 + a7 - ddl * 98) : (int)ZENT;
        const int st7 = ok7 ? 98 : 0;
        short8 A7g[8];
#pragma unroll
        for (int rz = 0; rz < 8; rz++) {
            int idx = cb7 + rz * st7;
            if (rz == 0) idx = (ddl == 0 && ok7) ? idx : (int)ZENT;
            if (rz == 7) idx = (ddl == 1 && ok7) ? idx : (int)ZENT;
            A7g[rz] = LDA(idx);
        }
        const int rowadd = (khg == 3) ? 6 : (2 * khg + khp);

#pragma unroll
        for (int zi = 0; zi < 14; zi++) {
            const int R = (zbase + zi) * HR + q + rowadd;
            const unsigned short* bp = &tile[R * RCOLS + 8 * kb];
            short8 B0 = *(const short8*)bp;
            short8 B1 = *(const short8*)(bp + 8);
            __builtin_amdgcn_s_setprio(1);
#pragma unroll
            for (int ddg = 0; ddg < 4; ddg++) {
                const int rz = zi - 2 * ddg;
                if (rz >= 0 && rz < 8) {
                    acc[ddg][0] = __builtin_amdgcn_mfma_f32_16x16x32_bf16(
                        A7g[rz], B0, acc[ddg][0], 0, 0, 0);
                    acc[ddg][1] = __builtin_amdgcn_mfma_f32_16x16x32_bf16(
                        A7g[rz], B1, acc[ddg][1], 0, 0, 0);
                }
            }
            __builtin_amdgcn_s_setprio(0);
        }
    }

    // ---- epilogue: y7 from acc, y3 from packed f16, x + 1x1 from LDS tile ----
#pragma unroll
    for (int ddg = 0; ddg < 4; ddg++) {
#pragma unroll
        for (int wh = 0; wh < 2; wh++) {
            const int d = d0 + zbase + 2 * ddg + khp;
            const int Rr = (zbase + 2 * ddg + khp + 3) * HR + (q + 3);
            uint2 u = *(const uint2*)&tile[Rr * RCOLS + 8 * wh + 4 * kb + 4];
            float xr[4];
            xr[0] = __builtin_bit_cast(float, u.x << 16);
            xr[1] = __builtin_bit_cast(float, u.x & 0xffff0000u);
            xr[2] = __builtin_bit_cast(float, u.y << 16);
            xr[3] = __builtin_bit_cast(float, u.y & 0xffff0000u);

            float2 y3lo = __half22float2(y3p[ddg][wh][0]);
            float2 y3hi = __half22float2(y3p[ddg][wh][1]);
            float y3v[4] = { y3lo.x, y3lo.y, y3hi.x, y3hi.y };

            size_t off = ((size_t)(nb * Cc + c) * Dd + d) * (Hh * Ww)
                       + (size_t)(h0 + q) * Ww + w0 + 8 * wh + 4 * kb;
            float o[4];
#pragma unroll
            for (int r = 0; r < 4; r++) {
                float y7 = fmaxf(fmaf(acc[ddg][wh][r], iv7, bb7), 0.f);
                float y1 = fmaxf(fmaf(xr[r], s1, bb1), 0.f);
                o[r] = fmaxf(xr[r] + y7 + y3v[r] + y1, 0.f);
            }
            *(float4*)(out + off) = make_float4(o[0], o[1], o[2], o[3]);
        }
    }
}

extern "C" void kernel_launch(void* const* d_in, const int* in_sizes, int n_in,
                              void* d_out, int out_size, void* d_ws, size_t ws_size,
                              hipStream_t stream) {
    const float* x  = (const float*)d_in[0];
    const float* w7 = (const float*)d_in[1];
    const float* w3 = (const float*)d_in[2];
    const float* w1 = (const float*)d_in[3];
    const float* g7 = (const float*)d_in[4];
    const float* b7 = (const float*)d_in[5];
    const float* m7 = (const float*)d_in[6];
    const float* v7 = (const float*)d_in[7];
    const float* g3 = (const float*)d_in[8];
    const float* b3 = (const float*)d_in[9];
    const float* m3 = (const float*)d_in[10];
    const float* v3 = (const float*)d_in[11];
    const float* g1 = (const float*)d_in[12];
    const float* b1 = (const float*)d_in[13];
    const float* m1 = (const float*)d_in[14];
    const float* v1 = (const float*)d_in[15];
    float* out = (float*)d_out;
    uint4* gtab = (uint4*)d_ws;

    dim3 grid(8192);
    dim3 block(256);
    if (ws_size >= WTAB_BYTES) {
        hipLaunchKernelGGL((replk_mfma<true>), grid, block, 0, stream,
                           x, w7, w3, w1, g7, b7, m7, v7, g3, b3, m3, v3,
                           g1, b1, m1, v1, gtab, out);
    } else {
        hipLaunchKernelGGL((replk_mfma<false>), grid, block, 0, stream,
                           x, w7, w3, w1, g7, b7, m7, v7, g3, b3, m3, v3,
                           g1, b1, m1, v1, gtab, out);
    }
}

// Round 13
// 276.782 us; speedup vs baseline: 5.9753x; 5.9753x over previous
//
#include <hip/hip_runtime.h>
#include <hip/hip_bf16.h>

#define Dd 64
#define Hh 128
#define Ww 128
#define Cc 32

// block tile: 32d x 16h x 16w outputs; wave = 8d x 16h x 16w
#define BD 32
#define BH 16
#define BW 16
#define ZR (BD + 6)        // 38 staged z-planes
#define HR (BH + 6)        // 22 staged h-rows
#define NR (ZR * HR)       // 836 rows
#define RCOLS 24           // bf16 cols per row; col = w - w0 + 4 (left halo 4)
#define BLKROW 3
#define NBLK (NR * BLKROW) // 2508 16B blocks to stage

// A-fragment table: 49 7^3-planes x 14 windows + 9 3^3-planes x 10 windows
// + 1 shared all-zero entry. 777 entries x 16B = 12432 B (in LDS — r12 proved
// global-table rebuild-per-block causes L2 write storms + fence stalls).
#define N7WIN 14
#define N3WIN 10
#define W3BASE (49 * N7WIN)          // 686
#define ZENT   (W3BASE + 9 * N3WIN) // 776
#define NENT   (ZENT + 1)           // 777

typedef __attribute__((ext_vector_type(8))) short short8;   // 8 bf16 (4 VGPR)
typedef __attribute__((ext_vector_type(4))) float floatx4;  // MFMA acc

static __device__ __forceinline__ unsigned short f2bf(float f) {
    unsigned u = __builtin_bit_cast(unsigned, f);
    u += 0x7fffu + ((u >> 16) & 1u);   // RNE
    return (unsigned short)(u >> 16);
}

static __device__ __forceinline__ unsigned pk2(float a, float b) {
    union { __hip_bfloat162 h; unsigned u; } cv;
    cv.h = __float22bfloat162_rn(make_float2(a, b));   // v_cvt_pk_bf16_f32
    return cv.u;
}

// Scheme-2 MFMA mapping (16x16x32):
//   M = (ddl, mw), K = (khp, wc), N = h-row. Per-lane: q = lane&15 (m|n),
//   p = lane>>4 -> khp = p>>1, kb = p&1 (16B block of wc).
// LDS anti-conflict: the 3 16B blocks of row R are rotated by (R>>1)%3
// (slot = (bl + (R>>1))%3) — breaks the q/q+8 and q/q+2 bank aliases of the
// 48B (12-bank) row pitch. (R>>1) is affine in zi: (r0>>1) + 11*zi.
__global__ __launch_bounds__(256, 3) void replk_mfma(
    const float* __restrict__ x,
    const float* __restrict__ w7, const float* __restrict__ w3, const float* __restrict__ w1,
    const float* __restrict__ g7, const float* __restrict__ b7, const float* __restrict__ m7, const float* __restrict__ v7,
    const float* __restrict__ g3, const float* __restrict__ b3, const float* __restrict__ m3, const float* __restrict__ v3,
    const float* __restrict__ g1, const float* __restrict__ b1, const float* __restrict__ m1, const float* __restrict__ v1,
    float* __restrict__ out)
{
    __shared__ __align__(16) unsigned short tile[NR * RCOLS];  // 40128 B
    __shared__ __align__(16) unsigned short wtab[NENT * 8];    // 12432 B
    // 52560 raw -> 53248 granule; x3 = 159744 <= 160 KiB -> 3 blocks/CU

    const int tid = threadIdx.x;

    // XCD-aware swizzle: 8192 blocks, 8 XCDs, 1024 contiguous per XCD.
    const unsigned lid = blockIdx.x;
    const unsigned nl = (lid & 7u) * 1024u + (lid >> 3);
    const int bx = nl & 127;
    const int slab = nl >> 7;
    const int c = slab & 31;
    const int nb = slab >> 5;
    const int w0 = (bx & 7) * BW;
    const int h0 = ((bx >> 3) & 7) * BH;
    const int d0 = (bx >> 6) * BD;

    const float* xc = x + (size_t)(nb * Cc + c) * (Dd * Hh * Ww);

    // ---- build A-fragment table in LDS (r10/r11 layout, verified) ----
    for (int e = tid; e < NENT; e += 256) {
        unsigned short h8[8];
#pragma unroll
        for (int j = 0; j < 8; j++) {
            float v = 0.f;
            if (e < W3BASE) {
                int pl = e / N7WIN, a = e - pl * N7WIN;
                int t = a + j - 7;
                if ((unsigned)t < 7u)
                    v = w7[c * 343 + (pl / 7) * 49 + (pl % 7) * 7 + t];
            } else if (e < ZENT) {
                int e2 = e - W3BASE;
                int p3 = e2 / N3WIN, a = e2 - p3 * N3WIN;
                int t = a + j - 7;
                if ((unsigned)t < 3u)
                    v = w3[c * 27 + (p3 / 3) * 9 + (p3 % 3) * 3 + t];
            }
            h8[j] = f2bf(v);
        }
        uint4 pk;
        pk.x = (unsigned)h8[0] | ((unsigned)h8[1] << 16);
        pk.y = (unsigned)h8[2] | ((unsigned)h8[3] << 16);
        pk.z = (unsigned)h8[4] | ((unsigned)h8[5] << 16);
        pk.w = (unsigned)h8[6] | ((unsigned)h8[7] << 16);
        *(uint4*)&wtab[e * 8] = pk;
    }

    // ---- stage input tile fp32 -> bf16, rotated block slots ----
#pragma unroll
    for (int it = 0; it < 10; it++) {
        int s = tid + it * 256;
        if (s < NBLK) {
            int R = s / BLKROW, bl = s - R * BLKROW;
            int zi = R / HR, hr = R - zi * HR;
            int gz = d0 - 3 + zi, gh = h0 - 3 + hr, gw0 = w0 - 4 + bl * 8;
            float v[8];
#pragma unroll
            for (int j = 0; j < 8; j++) v[j] = 0.f;
            if ((unsigned)gz < (unsigned)Dd && (unsigned)gh < (unsigned)Hh) {
                const float* src = xc + ((size_t)gz * Hh + gh) * Ww + gw0;
                if (gw0 >= 0 && gw0 + 8 <= Ww) {
                    float4 a = *(const float4*)src;
                    float4 b = *(const float4*)(src + 4);
                    v[0] = a.x; v[1] = a.y; v[2] = a.z; v[3] = a.w;
                    v[4] = b.x; v[5] = b.y; v[6] = b.z; v[7] = b.w;
                } else {
#pragma unroll
                    for (int j = 0; j < 8; j++) {
                        int gw = gw0 + j;
                        if ((unsigned)gw < (unsigned)Ww) v[j] = src[j];
                    }
                }
            }
            uint4 pk;
            pk.x = pk2(v[0], v[1]);
            pk.y = pk2(v[2], v[3]);
            pk.z = pk2(v[4], v[5]);
            pk.w = pk2(v[6], v[7]);
            int sl = bl + ((R >> 1) % 3);
            if (sl >= 3) sl -= 3;
            *(uint4*)&tile[R * RCOLS + sl * 8] = pk;
        }
    }

    // BN constants (wave-uniform)
    const float eps = 1e-5f;
    const float iv7 = g7[c] / sqrtf(v7[c] + eps);
    const float bb7 = b7[c] - m7[c] * iv7;
    const float iv3 = g3[c] / sqrtf(v3[c] + eps);
    const float bb3 = b3[c] - m3[c] * iv3;
    const float iv1 = g1[c] / sqrtf(v1[c] + eps);
    const float bb1 = b1[c] - m1[c] * iv1;
    const float s1 = w1[c] * iv1;

    __syncthreads();

    const int lane = tid & 63;
    const int wave = tid >> 6;
    const int q = lane & 15;          // m (A) / n (B,C,D)
    const int p = lane >> 4;
    const int khp = p >> 1;           // kh within pair
    const int kb  = p & 1;            // wc 16B-block
    const int ddl = q >> 3;           // d within M-pair (A side)
    const int mwq = q & 7;            // w within M (A side)
    const int zbase = wave * 8;       // wave owns d-outputs [zbase, zbase+8)

    const int a7 = 8 * kb - mwq + 6;  // 7^3 window (valid [0,14))
    const int a3 = a7 - 2;            // 3^3 window (valid [0,10))
    const short8* wf = (const short8*)wtab;

    floatx4 acc7[4][2], acc3[4][2];
#pragma unroll
    for (int i = 0; i < 4; i++)
#pragma unroll
        for (int wh = 0; wh < 2; wh++) { acc7[i][wh] = (floatx4)0.f; acc3[i][wh] = (floatx4)0.f; }

    // ---- khg-outer loop: kh-pairs {0,1}{2,3}{4,5}{6,-}; 3^3 shares B of khg 1,2 ----
#pragma unroll 1
    for (int khg = 0; khg < 4; khg++) {
        const int kh = 2 * khg + khp;                       // 0..7 (7 = zero)
        const bool ok7 = ((unsigned)a7 < 14u) && (kh <= 6);
        const int cb7 = ok7 ? (kh * 14 + a7 - ddl * 98) : (int)ZENT;
        const int st7 = ok7 ? 98 : 0;
        short8 A7g[8];
#pragma unroll
        for (int rz = 0; rz < 8; rz++) {
            int idx = cb7 + rz * st7;
            if (rz == 0) idx = (ddl == 0 && ok7) ? idx : (int)ZENT;  // kd=-1 lanes
            if (rz == 7) idx = (ddl == 1 && ok7) ? idx : (int)ZENT;  // kd=7 lanes
            A7g[rz] = wf[idx];
        }

        const bool has3 = (khg == 1) || (khg == 2);
        short8 A3g[4] = {};
        if (has3) {
            const int kh3 = 2 * (khg - 1) + khp;            // 0..3 (3 = zero)
            const bool ok3 = ((unsigned)a3 < 10u) && (kh3 <= 2);
            const int cb3 = ok3 ? (W3BASE + kh3 * 10 + a3 - ddl * 30) : (int)ZENT;
            const int st3 = ok3 ? 30 : 0;
#pragma unroll
            for (int rz = 0; rz < 4; rz++) {
                int idx = cb3 + rz * st3;
                if (rz == 0) idx = (ddl == 0 && ok3) ? idx : (int)ZENT;
                if (rz == 3) idx = (ddl == 1 && ok3) ? idx : (int)ZENT;
                A3g[rz] = wf[idx];
            }
        }

        // kh=7 lanes (khg=3, khp=1) have zero A: clamp their B row to kh=6's.
        const int rowadd = (khg == 3) ? 6 : (2 * khg + khp);

        // rotation state: R = r0 + 22*zi, (R>>1) = (r0>>1) + 11*zi (22*zi even)
        const int r0 = zbase * HR + q + rowadd;
        int e0 = (kb + (r0 >> 1)) % 3;          // slot of block kb at zi=0
        int e1 = e0 + 1; if (e1 >= 3) e1 -= 3;  // slot of block kb+1

#pragma unroll
        for (int zi = 0; zi < 14; zi++) {
            const int R = (zbase + zi) * HR + q + rowadd;
            const int z3 = (2 * zi) % 3;        // compile-time per unrolled zi
            int s0 = e0 + z3; if (s0 >= 3) s0 -= 3;
            int s1h = e1 + z3; if (s1h >= 3) s1h -= 3;
            const unsigned short* rowp = &tile[R * RCOLS];
            short8 B0 = *(const short8*)(rowp + s0 * 8);
            short8 B1 = *(const short8*)(rowp + s1h * 8);
            __builtin_amdgcn_s_setprio(1);
#pragma unroll
            for (int ddg = 0; ddg < 4; ddg++) {
                const int rz = zi - 2 * ddg;
                if (rz >= 0 && rz < 8) {
                    acc7[ddg][0] = __builtin_amdgcn_mfma_f32_16x16x32_bf16(
                        A7g[rz], B0, acc7[ddg][0], 0, 0, 0);
                    acc7[ddg][1] = __builtin_amdgcn_mfma_f32_16x16x32_bf16(
                        A7g[rz], B1, acc7[ddg][1], 0, 0, 0);
                }
            }
            if (has3) {
#pragma unroll
                for (int ddg = 0; ddg < 4; ddg++) {
                    const int rz3 = zi - 2 - 2 * ddg;
                    if (rz3 >= 0 && rz3 < 4) {
                        acc3[ddg][0] = __builtin_amdgcn_mfma_f32_16x16x32_bf16(
                            A3g[rz3], B0, acc3[ddg][0], 0, 0, 0);
                        acc3[ddg][1] = __builtin_amdgcn_mfma_f32_16x16x32_bf16(
                            A3g[rz3], B1, acc3[ddg][1], 0, 0, 0);
                    }
                }
            }
            __builtin_amdgcn_s_setprio(0);
        }
    }

    // ---- epilogue: C/D col n=q (h), row m=4p+r; residual x from LDS tile ----
    // target cols 8wh+4kb+4+{0..3} live in block be = wh+kb, inner shorts 4-4*kb
#pragma unroll
    for (int ddg = 0; ddg < 4; ddg++) {
#pragma unroll
        for (int wh = 0; wh < 2; wh++) {
            const int d = d0 + zbase + 2 * ddg + khp;
            const int Rr = (zbase + 2 * ddg + khp + 3) * HR + (q + 3);
            int se = wh + kb + ((Rr >> 1) % 3);
            if (se >= 3) se -= 3;
            const unsigned short* ep = &tile[Rr * RCOLS + se * 8 + (4 - 4 * kb)];
            uint2 u = *(const uint2*)ep;   // 8B-aligned
            float xr[4];
            xr[0] = __builtin_bit_cast(float, u.x << 16);
            xr[1] = __builtin_bit_cast(float, u.x & 0xffff0000u);
            xr[2] = __builtin_bit_cast(float, u.y << 16);
            xr[3] = __builtin_bit_cast(float, u.y & 0xffff0000u);

            size_t off = ((size_t)(nb * Cc + c) * Dd + d) * (Hh * Ww)
                       + (size_t)(h0 + q) * Ww + w0 + 8 * wh + 4 * kb;
            float o[4];
#pragma unroll
            for (int r = 0; r < 4; r++) {
                float y7 = fmaxf(fmaf(acc7[ddg][wh][r], iv7, bb7), 0.f);
                float y3 = fmaxf(fmaf(acc3[ddg][wh][r], iv3, bb3), 0.f);
                float y1 = fmaxf(fmaf(xr[r], s1, bb1), 0.f);
                o[r] = fmaxf(xr[r] + y7 + y3 + y1, 0.f);
            }
            *(float4*)(out + off) = make_float4(o[0], o[1], o[2], o[3]);
        }
    }
}

extern "C" void kernel_launch(void* const* d_in, const int* in_sizes, int n_in,
                              void* d_out, int out_size, void* d_ws, size_t ws_size,
                              hipStream_t stream) {
    const float* x  = (const float*)d_in[0];
    const float* w7 = (const float*)d_in[1];
    const float* w3 = (const float*)d_in[2];
    const float* w1 = (const float*)d_in[3];
    const float* g7 = (const float*)d_in[4];
    const float* b7 = (const float*)d_in[5];
    const float* m7 = (const float*)d_in[6];
    const float* v7 = (const float*)d_in[7];
    const float* g3 = (const float*)d_in[8];
    const float* b3 = (const float*)d_in[9];
    const float* m3 = (const float*)d_in[10];
    const float* v3 = (const float*)d_in[11];
    const float* g1 = (const float*)d_in[12];
    const float* b1 = (const float*)d_in[13];
    const float* m1 = (const float*)d_in[14];
    const float* v1 = (const float*)d_in[15];
    float* out = (float*)d_out;

    dim3 grid(8192);   // 1-D; kernel swizzles to (slab, tile) XCD-contiguously
    dim3 block(256);
    hipLaunchKernelGGL(replk_mfma, grid, block, 0, stream,
                       x, w7, w3, w1, g7, b7, m7, v7, g3, b3, m3, v3,
                       g1, b1, m1, v1, out);
}

// Round 14
// 260.534 us; speedup vs baseline: 6.3479x; 1.0624x over previous
//
#include <hip/hip_runtime.h>
#include <hip/hip_bf16.h>

#define Dd 64
#define Hh 128
#define Ww 128
#define Cc 32

// block tile: 32d x 16h x 16w outputs; wave = 8d x 16h x 16w
#define BD 32
#define BH 16
#define BW 16
#define ZR (BD + 6)        // 38 staged z-planes
#define HR (BH + 6)        // 22 staged h-rows
#define NR (ZR * HR)       // 836 rows
#define RCOLS 24           // bf16 cols per row; col = w - w0 + 4 (left halo 4)
#define BLKROW 3
#define NBLK (NR * BLKROW) // 2508 16B blocks to stage

// A-fragment table: 49 7^3-planes x 14 windows + 9 3^3-planes x 10 windows
// + 1 shared all-zero entry. 777 entries x 16B = 12432 B in LDS.
// (r12 proved global-table rebuild-per-block = L2 write storm; r13 proved the
//  (R>>1)%3 slot rotation made banks WORSE — linear slots are uniform 2-way = free.)
#define N7WIN 14
#define N3WIN 10
#define W3BASE (49 * N7WIN)          // 686
#define ZENT   (W3BASE + 9 * N3WIN) // 776
#define NENT   (ZENT + 1)           // 777

typedef __attribute__((ext_vector_type(8))) short short8;   // 8 bf16 (4 VGPR)
typedef __attribute__((ext_vector_type(4))) float floatx4;  // MFMA acc

static __device__ __forceinline__ unsigned short f2bf(float f) {
    unsigned u = __builtin_bit_cast(unsigned, f);
    u += 0x7fffu + ((u >> 16) & 1u);   // RNE
    return (unsigned short)(u >> 16);
}

static __device__ __forceinline__ unsigned pk2(float a, float b) {
    union { __hip_bfloat162 h; unsigned u; } cv;
    cv.h = __float22bfloat162_rn(make_float2(a, b));   // v_cvt_pk_bf16_f32
    return cv.u;
}

// Scheme-2 MFMA mapping (16x16x32):
//   M = (ddl, mw), K = (khp, wc), N = h-row. Per-lane: q = lane&15 (m|n),
//   p = lane>>4 -> khp = p>>1, kb = p&1 (16B block of wc).
// No setprio in the main loop (r14): the per-zi s_setprio pair is a plausible
// compiler scheduling fence blocking B-read hoisting across zi iterations.
__global__ __launch_bounds__(256, 3) void replk_mfma(
    const float* __restrict__ x,
    const float* __restrict__ w7, const float* __restrict__ w3, const float* __restrict__ w1,
    const float* __restrict__ g7, const float* __restrict__ b7, const float* __restrict__ m7, const float* __restrict__ v7,
    const float* __restrict__ g3, const float* __restrict__ b3, const float* __restrict__ m3, const float* __restrict__ v3,
    const float* __restrict__ g1, const float* __restrict__ b1, const float* __restrict__ m1, const float* __restrict__ v1,
    float* __restrict__ out)
{
    __shared__ __align__(16) unsigned short tile[NR * RCOLS];  // 40128 B
    __shared__ __align__(16) unsigned short wtab[NENT * 8];    // 12432 B
    // 52560 raw -> 53248 granule; x3 = 159744 <= 160 KiB -> 3 blocks/CU

    const int tid = threadIdx.x;

    // XCD-aware swizzle: 8192 blocks, 8 XCDs, 1024 contiguous per XCD.
    const unsigned lid = blockIdx.x;
    const unsigned nl = (lid & 7u) * 1024u + (lid >> 3);
    const int bx = nl & 127;
    const int slab = nl >> 7;
    const int c = slab & 31;
    const int nb = slab >> 5;
    const int w0 = (bx & 7) * BW;
    const int h0 = ((bx >> 3) & 7) * BH;
    const int d0 = (bx >> 6) * BD;

    const float* xc = x + (size_t)(nb * Cc + c) * (Dd * Hh * Ww);

    // ---- build A-fragment table in LDS (r10/r11 layout, verified) ----
    for (int e = tid; e < NENT; e += 256) {
        unsigned short h8[8];
#pragma unroll
        for (int j = 0; j < 8; j++) {
            float v = 0.f;
            if (e < W3BASE) {
                int pl = e / N7WIN, a = e - pl * N7WIN;
                int t = a + j - 7;
                if ((unsigned)t < 7u)
                    v = w7[c * 343 + (pl / 7) * 49 + (pl % 7) * 7 + t];
            } else if (e < ZENT) {
                int e2 = e - W3BASE;
                int p3 = e2 / N3WIN, a = e2 - p3 * N3WIN;
                int t = a + j - 7;
                if ((unsigned)t < 3u)
                    v = w3[c * 27 + (p3 / 3) * 9 + (p3 % 3) * 3 + t];
            }
            h8[j] = f2bf(v);
        }
        uint4 pk;
        pk.x = (unsigned)h8[0] | ((unsigned)h8[1] << 16);
        pk.y = (unsigned)h8[2] | ((unsigned)h8[3] << 16);
        pk.z = (unsigned)h8[4] | ((unsigned)h8[5] << 16);
        pk.w = (unsigned)h8[6] | ((unsigned)h8[7] << 16);
        *(uint4*)&wtab[e * 8] = pk;
    }

    // ---- stage input tile fp32 -> bf16 (cvt_pk), 24 cols/row, linear slots ----
#pragma unroll
    for (int it = 0; it < 10; it++) {
        int s = tid + it * 256;
        if (s < NBLK) {
            int R = s / BLKROW, bl = s - R * BLKROW;
            int zi = R / HR, hr = R - zi * HR;
            int gz = d0 - 3 + zi, gh = h0 - 3 + hr, gw0 = w0 - 4 + bl * 8;
            float v[8];
#pragma unroll
            for (int j = 0; j < 8; j++) v[j] = 0.f;
            if ((unsigned)gz < (unsigned)Dd && (unsigned)gh < (unsigned)Hh) {
                const float* src = xc + ((size_t)gz * Hh + gh) * Ww + gw0;
                if (gw0 >= 0 && gw0 + 8 <= Ww) {
                    float4 a = *(const float4*)src;
                    float4 b = *(const float4*)(src + 4);
                    v[0] = a.x; v[1] = a.y; v[2] = a.z; v[3] = a.w;
                    v[4] = b.x; v[5] = b.y; v[6] = b.z; v[7] = b.w;
                } else {
#pragma unroll
                    for (int j = 0; j < 8; j++) {
                        int gw = gw0 + j;
                        if ((unsigned)gw < (unsigned)Ww) v[j] = src[j];
                    }
                }
            }
            uint4 pk;
            pk.x = pk2(v[0], v[1]);
            pk.y = pk2(v[2], v[3]);
            pk.z = pk2(v[4], v[5]);
            pk.w = pk2(v[6], v[7]);
            *(uint4*)&tile[R * RCOLS + bl * 8] = pk;
        }
    }

    // BN constants (wave-uniform)
    const float eps = 1e-5f;
    const float iv7 = g7[c] / sqrtf(v7[c] + eps);
    const float bb7 = b7[c] - m7[c] * iv7;
    const float iv3 = g3[c] / sqrtf(v3[c] + eps);
    const float bb3 = b3[c] - m3[c] * iv3;
    const float iv1 = g1[c] / sqrtf(v1[c] + eps);
    const float bb1 = b1[c] - m1[c] * iv1;
    const float s1 = w1[c] * iv1;

    __syncthreads();

    const int lane = tid & 63;
    const int wave = tid >> 6;
    const int q = lane & 15;          // m (A) / n (B,C,D)
    const int p = lane >> 4;
    const int khp = p >> 1;           // kh within pair
    const int kb  = p & 1;            // wc 16B-block
    const int ddl = q >> 3;           // d within M-pair (A side)
    const int mwq = q & 7;            // w within M (A side)
    const int zbase = wave * 8;       // wave owns d-outputs [zbase, zbase+8)

    const int a7 = 8 * kb - mwq + 6;  // 7^3 window (valid [0,14))
    const int a3 = a7 - 2;            // 3^3 window (valid [0,10))
    const short8* wf = (const short8*)wtab;

    floatx4 acc7[4][2], acc3[4][2];
#pragma unroll
    for (int i = 0; i < 4; i++)
#pragma unroll
        for (int wh = 0; wh < 2; wh++) { acc7[i][wh] = (floatx4)0.f; acc3[i][wh] = (floatx4)0.f; }

    // ---- khg-outer loop: kh-pairs {0,1}{2,3}{4,5}{6,-}; 3^3 shares B of khg 1,2 ----
#pragma unroll 1
    for (int khg = 0; khg < 4; khg++) {
        const int kh = 2 * khg + khp;                       // 0..7 (7 = zero)
        const bool ok7 = ((unsigned)a7 < 14u) && (kh <= 6);
        const int cb7 = ok7 ? (kh * 14 + a7 - ddl * 98) : (int)ZENT;
        const int st7 = ok7 ? 98 : 0;
        short8 A7g[8];
#pragma unroll
        for (int rz = 0; rz < 8; rz++) {
            int idx = cb7 + rz * st7;
            if (rz == 0) idx = (ddl == 0 && ok7) ? idx : (int)ZENT;  // kd=-1 lanes
            if (rz == 7) idx = (ddl == 1 && ok7) ? idx : (int)ZENT;  // kd=7 lanes
            A7g[rz] = wf[idx];
        }

        const bool has3 = (khg == 1) || (khg == 2);
        short8 A3g[4] = {};
        if (has3) {
            const int kh3 = 2 * (khg - 1) + khp;            // 0..3 (3 = zero)
            const bool ok3 = ((unsigned)a3 < 10u) && (kh3 <= 2);
            const int cb3 = ok3 ? (W3BASE + kh3 * 10 + a3 - ddl * 30) : (int)ZENT;
            const int st3 = ok3 ? 30 : 0;
#pragma unroll
            for (int rz = 0; rz < 4; rz++) {
                int idx = cb3 + rz * st3;
                if (rz == 0) idx = (ddl == 0 && ok3) ? idx : (int)ZENT;
                if (rz == 3) idx = (ddl == 1 && ok3) ? idx : (int)ZENT;
                A3g[rz] = wf[idx];
            }
        }

        // kh=7 lanes (khg=3, khp=1) have zero A: clamp their B row to kh=6's.
        const int rowadd = (khg == 3) ? 6 : (2 * khg + khp);

#pragma unroll
        for (int zi = 0; zi < 14; zi++) {
            const int R = (zbase + zi) * HR + q + rowadd;
            const unsigned short* bp = &tile[R * RCOLS + 8 * kb];
            short8 B0 = *(const short8*)bp;
            short8 B1 = *(const short8*)(bp + 8);
#pragma unroll
            for (int ddg = 0; ddg < 4; ddg++) {
                const int rz = zi - 2 * ddg;
                if (rz >= 0 && rz < 8) {
                    acc7[ddg][0] = __builtin_amdgcn_mfma_f32_16x16x32_bf16(
                        A7g[rz], B0, acc7[ddg][0], 0, 0, 0);
                    acc7[ddg][1] = __builtin_amdgcn_mfma_f32_16x16x32_bf16(
                        A7g[rz], B1, acc7[ddg][1], 0, 0, 0);
                }
            }
            if (has3) {
#pragma unroll
                for (int ddg = 0; ddg < 4; ddg++) {
                    const int rz3 = zi - 2 - 2 * ddg;
                    if (rz3 >= 0 && rz3 < 4) {
                        acc3[ddg][0] = __builtin_amdgcn_mfma_f32_16x16x32_bf16(
                            A3g[rz3], B0, acc3[ddg][0], 0, 0, 0);
                        acc3[ddg][1] = __builtin_amdgcn_mfma_f32_16x16x32_bf16(
                            A3g[rz3], B1, acc3[ddg][1], 0, 0, 0);
                    }
                }
            }
        }
    }

    // ---- epilogue: C/D col n=q (h), row m=4p+r; residual x from LDS tile ----
#pragma unroll
    for (int ddg = 0; ddg < 4; ddg++) {
#pragma unroll
        for (int wh = 0; wh < 2; wh++) {
            const int d = d0 + zbase + 2 * ddg + khp;
            const int Rr = (zbase + 2 * ddg + khp + 3) * HR + (q + 3);
            uint2 u = *(const uint2*)&tile[Rr * RCOLS + 8 * wh + 4 * kb + 4];
            float xr[4];
            xr[0] = __builtin_bit_cast(float, u.x << 16);
            xr[1] = __builtin_bit_cast(float, u.x & 0xffff0000u);
            xr[2] = __builtin_bit_cast(float, u.y << 16);
            xr[3] = __builtin_bit_cast(float, u.y & 0xffff0000u);

            float2 dummy;
            size_t off = ((size_t)(nb * Cc + c) * Dd + d) * (Hh * Ww)
                       + (size_t)(h0 + q) * Ww + w0 + 8 * wh + 4 * kb;
            float o[4];
#pragma unroll
            for (int r = 0; r < 4; r++) {
                float y7 = fmaxf(fmaf(acc7[ddg][wh][r], iv7, bb7), 0.f);
                float y3 = fmaxf(fmaf(acc3[ddg][wh][r], iv3, bb3), 0.f);
                float y1 = fmaxf(fmaf(xr[r], s1, bb1), 0.f);
                o[r] = fmaxf(xr[r] + y7 + y3 + y1, 0.f);
            }
            *(float4*)(out + off) = make_float4(o[0], o[1], o[2], o[3]);
        }
    }
}

extern "C" void kernel_launch(void* const* d_in, const int* in_sizes, int n_in,
                              void* d_out, int out_size, void* d_ws, size_t ws_size,
                              hipStream_t stream) {
    const float* x  = (const float*)d_in[0];
    const float* w7 = (const float*)d_in[1];
    const float* w3 = (const float*)d_in[2];
    const float* w1 = (const float*)d_in[3];
    const float* g7 = (const float*)d_in[4];
    const float* b7 = (const float*)d_in[5];
    const float* m7 = (const float*)d_in[6];
    const float* v7 = (const float*)d_in[7];
    const float* g3 = (const float*)d_in[8];
    const float* b3 = (const float*)d_in[9];
    const float* m3 = (const float*)d_in[10];
    const float* v3 = (const float*)d_in[11];
    const float* g1 = (const float*)d_in[12];
    const float* b1 = (const float*)d_in[13];
    const float* m1 = (const float*)d_in[14];
    const float* v1 = (const float*)d_in[15];
    float* out = (float*)d_out;

    dim3 grid(8192);   // 1-D; kernel swizzles to (slab, tile) XCD-contiguously
    dim3 block(256);
    hipLaunchKernelGGL(replk_mfma, grid, block, 0, stream,
                       x, w7, w3, w1, g7, b7, m7, v7, g3, b3, m3, v3,
                       g1, b1, m1, v1, out);
}